// Round 9
// baseline (195.582 us; speedup 1.0000x reference)
//
#include <hip/hip_runtime.h>
#include <hip/hip_bf16.h>

#define B_   4
#define H_   16
#define L_   2048
#define DH_  64
#define QSCALE 0.1803368801111204f  // (1/sqrt(64)) * log2(e): scores in log2 domain
#define LDK  72                     // fallback-kernel padded stride

typedef __bf16 bf16;
typedef __bf16 bf16x4 __attribute__((ext_vector_type(4)));
typedef __bf16 bf16x8 __attribute__((ext_vector_type(8)));
typedef float  f32x4  __attribute__((ext_vector_type(4)));

// ---------------- prep: K -> bf16 swizzled [bh][key][64], V -> bf16 transposed
// swizzled [bh][dh][2048].  Swizzle: within each 128B row/segment, 16B block c
// stored at slot c ^ (row & 7).  (Unchanged, proven.)
__global__ __launch_bounds__(256, 4)
void prep(const float* __restrict__ K, const float* __restrict__ V,
          bf16* __restrict__ Kb, bf16* __restrict__ Vtg)
{
    __shared__ bf16 tl[64 * 72];   // transposed V tile [dh][key], padded
    const int t   = threadIdx.x;
    const int r   = t >> 2;        // row 0..63
    const int c4  = t & 3;         // 16-col group
    const int bid = blockIdx.x;
    const int kt  = bid & 31;
    const int bh  = bid >> 5;

    const float* Kp = K + ((size_t)bh * L_ + kt * 64) * DH_;
    const float* Vp = V + ((size_t)bh * L_ + kt * 64) * DH_;
    bf16* Kbp = Kb  + (size_t)bh * (L_ * DH_) + (size_t)(kt * 64) * DH_;
    bf16* Vtp = Vtg + (size_t)bh * (DH_ * L_) + kt * 64;

    { // K: cvt + swizzle (row-major [key][dh])
        const float* src = Kp + r * DH_ + c4 * 16;
        f32x4 a = *(const f32x4*)(src);
        f32x4 b = *(const f32x4*)(src + 4);
        f32x4 c = *(const f32x4*)(src + 8);
        f32x4 d = *(const f32x4*)(src + 12);
        bf16x8 lo, hi;
        #pragma unroll
        for (int j = 0; j < 4; ++j) {
            lo[j] = (bf16)a[j]; lo[j + 4] = (bf16)b[j];
            hi[j] = (bf16)c[j]; hi[j + 4] = (bf16)d[j];
        }
        const int b0 = 2 * c4, b1 = 2 * c4 + 1;
        *(bf16x8*)(Kbp + r * 64 + (b0 ^ (r & 7)) * 8) = lo;
        *(bf16x8*)(Kbp + r * 64 + (b1 ^ (r & 7)) * 8) = hi;
    }
    { // V: cvt + transpose via LDS
        const float* src = Vp + r * DH_ + c4 * 16;
        f32x4 a = *(const f32x4*)(src);
        f32x4 b = *(const f32x4*)(src + 4);
        f32x4 c = *(const f32x4*)(src + 8);
        f32x4 d = *(const f32x4*)(src + 12);
        #pragma unroll
        for (int j = 0; j < 4; ++j) {
            tl[(c4 * 16 + j)      * 72 + r] = (bf16)a[j];
            tl[(c4 * 16 + 4 + j)  * 72 + r] = (bf16)b[j];
            tl[(c4 * 16 + 8 + j)  * 72 + r] = (bf16)c[j];
            tl[(c4 * 16 + 12 + j) * 72 + r] = (bf16)d[j];
        }
    }
    __syncthreads();
    { // write Vtg rows (dh-major), swizzled within the 64-key tile segment
        const int d = r;
        #pragma unroll
        for (int bi = 0; bi < 2; ++bi) {
            const int blk = 2 * c4 + bi;
            bf16x8 v;
            #pragma unroll
            for (int j = 0; j < 8; ++j) v[j] = tl[d * 72 + blk * 8 + j];
            *(bf16x8*)(Vtp + (size_t)d * L_ + (blk ^ (d & 7)) * 8) = v;
        }
    }
}

// ---------------- main: R12 — NO LDS staging, NO barriers: free-running waves.
// KV per bh = 512 KB bf16 and all 8 blocks of a bh sit on one XCD (u%8==bh%8)
// -> KV is L2-resident; each 16KB K/V tile L1-resident with 4-wave x 2-qg
// reuse. LDS staging of L2-fitting data is pure overhead (learn_hip m169) and
// its barriers phase-lock all waves. Here bk/bv read DIRECTLY from the prepped
// global buffers (byte-identical data: LDS was a verbatim copy, same swizzle
// indexing). Only per-wave P scratch remains in LDS (same-wave write->read,
// no cross-wave hazard) -> zero __syncthreads. Waves run at independent loop
// phases, overlapping MFMA / VALU / memory naturally.
// Geometry unchanged: Br=128, 32 rows/wave, 2 qg; 512 blocks; pass pair
// (pidx, 15-pidx) = 34 iters/block, perfectly balanced; masks/epilogue
// byte-identical to the R9/R11 passing code.
__global__ __launch_bounds__(256, 2)
void fa_fwd3(const float* __restrict__ Q, const bf16* __restrict__ Kb,
             const bf16* __restrict__ Vtg, float* __restrict__ O)
{
    __shared__ __align__(16) bf16 Pl[4][16 * 64];       // per-wave P scratch, 8 KB

    const int tid  = threadIdx.x;
    const int wave = tid >> 6;
    const int lane = tid & 63;
    const int quad = lane >> 4;
    const int l15  = lane & 15;

    const int u    = blockIdx.x;          // 512 blocks
    const int xcd  = u & 7;
    const int t    = u >> 3;              // 0..63
    const int bh   = xcd * 8 + (t & 7);   // bh%8==u%8 -> per-XCD KV L2 residency
    const int pidx = t >> 3;              // 0..7 -> pair (pidx, 15-pidx)

    const int h    = bh & 15;
    const int b    = bh >> 4;

    const float* Qbh = Q + (size_t)bh * L_ * DH_;
    const bf16* Kbh  = Kb  + (size_t)bh * (L_ * DH_);
    const bf16* Vbh  = Vtg + (size_t)bh * (DH_ * L_);

    bf16x8 vone;
    #pragma unroll
    for (int jj = 0; jj < 8; ++jj) vone[jj] = (bf16)1.0f;

    int swb[2];
    #pragma unroll
    for (int ss = 0; ss < 2; ++ss) swb[ss] = ((4 * ss + quad) ^ (l15 & 7)) * 8;

    for (int pass = 0; pass < 2; ++pass) {
        const int Qt   = pass ? (15 - pidx) : pidx;
        const int q0   = Qt * 128;
        const int jmax = 2 * Qt + 1;

        // Q frags as B-operand (B[k=dh][n=qrow]: n=l15, k=quad*8+j), scale folded
        bf16x8 qf[2][2];
        #pragma unroll
        for (int qg = 0; qg < 2; ++qg) {
            const int row = q0 + 32 * wave + 16 * qg + l15;
            const float* qp = Qbh + (size_t)row * DH_ + quad * 8;
            #pragma unroll
            for (int ss = 0; ss < 2; ++ss) {
                f32x4 a = *(const f32x4*)(qp + ss * 32);
                f32x4 c = *(const f32x4*)(qp + ss * 32 + 4);
                #pragma unroll
                for (int jj = 0; jj < 4; ++jj) {
                    qf[qg][ss][jj]     = (bf16)(a[jj] * QSCALE);
                    qf[qg][ss][jj + 4] = (bf16)(c[jj] * QSCALE);
                }
            }
        }

        f32x4 o_acc[2][4];
        f32x4 l_acc[2];
        #pragma unroll
        for (int qg = 0; qg < 2; ++qg) {
            l_acc[qg] = (f32x4)0.0f;
            #pragma unroll
            for (int ct = 0; ct < 4; ++ct) o_acc[qg][ct] = (f32x4)0.0f;
        }

        for (int j = 0; j <= jmax; ++j) {
            // fully-masked waves skip the 2nd diagonal tile entirely
            const bool active = (j < 2 * Qt) || ((32 * wave + 31) >= ((j - 2 * Qt) << 6));
            if (!active) continue;

            const int kv0 = j * 64;
            const bf16* Kt = Kbh + (size_t)kv0 * 64;   // K tile [key][64], swizzled

            // K frags straight from global/L1 (A[m=key]: m=l15, k=quad*8+jj)
            bf16x8 bk[4][2];
            #pragma unroll
            for (int ct = 0; ct < 4; ++ct)
                #pragma unroll
                for (int ss = 0; ss < 2; ++ss)
                    bk[ct][ss] = *(const bf16x8*)&Kt[(16 * ct + l15) * 64 + swb[ss]];

            // V frags issued early (in flight under S-MFMA + exp)
            bf16x8 bv[4][2];
            #pragma unroll
            for (int ct = 0; ct < 4; ++ct)
                #pragma unroll
                for (int ss = 0; ss < 2; ++ss)
                    bv[ct][ss] = *(const bf16x8*)&Vbh[(size_t)(16 * ct + l15) * L_ + kv0 + swb[ss]];

            bf16x8 pa[2][2];
            #pragma unroll
            for (int qg = 0; qg < 2; ++qg) {
                // Sᵀ: C-layout lane holds key=16ct+quad*4+r, qrow=l15
                f32x4 sacc[4];
                #pragma unroll
                for (int ct = 0; ct < 4; ++ct) {
                    f32x4 acc = (f32x4)0.0f;
                    #pragma unroll
                    for (int ss = 0; ss < 2; ++ss)
                        acc = __builtin_amdgcn_mfma_f32_16x16x32_bf16(bk[ct][ss], qf[qg][ss], acc, 0, 0, 0);
                    sacc[ct] = acc;
                }

                if (j >= 2 * Qt) {  // diagonal band: mask key > row - 64*(j-2Qt)
                    const int rlim = 32 * wave + 16 * qg + l15 - ((j - 2 * Qt) << 6);
                    #pragma unroll
                    for (int ct = 0; ct < 4; ++ct) {
                        #pragma unroll
                        for (int r = 0; r < 4; ++r)
                            if (16 * ct + quad * 4 + r > rlim) sacc[ct][r] = -1e30f;
                    }
                }

                // P = exp2(S), pack 4 consecutive keys (r=0..3) -> one b64 write
                #pragma unroll
                for (int ct = 0; ct < 4; ++ct) {
                    bf16x4 pk;
                    #pragma unroll
                    for (int r = 0; r < 4; ++r) pk[r] = (bf16)exp2f(sacc[ct][r]);
                    const int blk = 2 * ct + (quad >> 1);
                    *(bf16x4*)&Pl[wave][l15 * 64 + ((blk ^ (l15 & 7)) * 8) + (quad & 1) * 4] = pk;
                }
                // A-frag read back (same wave, compiler-ordered lgkmcnt)
                #pragma unroll
                for (int ss = 0; ss < 2; ++ss)
                    pa[qg][ss] = *(const bf16x8*)&Pl[wave][l15 * 64 + swb[ss]];
            }

            // O += P V ;  l += P * ones
            __builtin_amdgcn_s_setprio(1);
            #pragma unroll
            for (int ct = 0; ct < 4; ++ct)
                #pragma unroll
                for (int ss = 0; ss < 2; ++ss)
                    #pragma unroll
                    for (int qg = 0; qg < 2; ++qg)
                        o_acc[qg][ct] = __builtin_amdgcn_mfma_f32_16x16x32_bf16(pa[qg][ss], bv[ct][ss], o_acc[qg][ct], 0, 0, 0);
            #pragma unroll
            for (int qg = 0; qg < 2; ++qg)
                #pragma unroll
                for (int ss = 0; ss < 2; ++ss)
                    l_acc[qg] = __builtin_amdgcn_mfma_f32_16x16x32_bf16(pa[qg][ss], vone, l_acc[qg], 0, 0, 0);
            __builtin_amdgcn_s_setprio(0);
        }

        // epilogue: O / l (l replicated across lanes; C-layout row=quad*4+r)
        #pragma unroll
        for (int qg = 0; qg < 2; ++qg)
            #pragma unroll
            for (int r = 0; r < 4; ++r) {
                const float inv = 1.0f / l_acc[qg][r];
                const int qrow = q0 + 32 * wave + 16 * qg + quad * 4 + r;
                float* op = &O[((size_t)b * L_ + qrow) * (H_ * DH_) + h * DH_];
                #pragma unroll
                for (int ct = 0; ct < 4; ++ct)
                    op[16 * ct + l15] = o_acc[qg][ct][r] * inv;
            }
    }
}

// ---------------- fallback (R3 kernel) if ws too small ----------------
__global__ __launch_bounds__(256, 4)
void fa_fwd(const float* __restrict__ Q, const float* __restrict__ K,
            const float* __restrict__ V, float* __restrict__ O)
{
    __shared__ __align__(16) bf16 Kl[64 * LDK];
    __shared__ __align__(16) bf16 Vt[64 * LDK];
    __shared__ __align__(16) bf16 Pl[4][16 * LDK];

    const int tid  = threadIdx.x;
    const int wave = tid >> 6;
    const int lane = tid & 63;
    const int quad = lane >> 4;
    const int l15  = lane & 15;

    const int u    = blockIdx.x;
    const int xcd  = u & 7;
    const int p    = u >> 3;
    const int bh   = xcd * 8 + (p & 7);
    const int pidx = p >> 3;
    const int h    = bh & 15;
    const int b    = bh >> 4;

    const float* Qbh = Q + (size_t)bh * L_ * DH_;
    const float* Kbh = K + (size_t)bh * L_ * DH_;
    const float* Vbh = V + (size_t)bh * L_ * DH_;

    const int r0 = tid >> 4;
    const int c0 = (tid & 15) * 4;

    for (int pass = 0; pass < 2; ++pass) {
        const int qt = pass ? (31 - pidx) : pidx;
        const int q0 = qt * 64;

        bf16x8 qf[2];
        {
            const int row = q0 + wave * 16 + l15;
            const float* qp = Qbh + (size_t)row * DH_ + quad * 8;
            #pragma unroll
            for (int s = 0; s < 2; ++s) {
                f32x4 a = *(const f32x4*)(qp + s * 32);
                f32x4 c = *(const f32x4*)(qp + s * 32 + 4);
                #pragma unroll
                for (int jj = 0; jj < 4; ++jj) {
                    qf[s][jj]     = (bf16)(a[jj] * QSCALE);
                    qf[s][jj + 4] = (bf16)(c[jj] * QSCALE);
                }
            }
        }

        float m_run[4], l_run[4];
        f32x4 o_acc[4];
        #pragma unroll
        for (int r = 0; r < 4; ++r) { m_run[r] = -1e30f; l_run[r] = 0.0f; }
        #pragma unroll
        for (int ct = 0; ct < 4; ++ct) o_acc[ct] = (f32x4)0.0f;

        f32x4 kreg[4], vreg[4];
        #pragma unroll
        for (int i = 0; i < 4; ++i) {
            kreg[i] = *(const f32x4*)(Kbh + (size_t)(r0 + 16 * i) * DH_ + c0);
            vreg[i] = *(const f32x4*)(Vbh + (size_t)(r0 + 16 * i) * DH_ + c0);
        }

        for (int j = 0; j <= qt; ++j) {
            __syncthreads();
            #pragma unroll
            for (int i = 0; i < 4; ++i) {
                const int row = r0 + 16 * i;
                bf16x4 kb;
                #pragma unroll
                for (int c = 0; c < 4; ++c) kb[c] = (bf16)kreg[i][c];
                *(bf16x4*)&Kl[row * LDK + c0] = kb;
                Vt[(c0 + 0) * LDK + row] = (bf16)vreg[i][0];
                Vt[(c0 + 1) * LDK + row] = (bf16)vreg[i][1];
                Vt[(c0 + 2) * LDK + row] = (bf16)vreg[i][2];
                Vt[(c0 + 3) * LDK + row] = (bf16)vreg[i][3];
            }
            __syncthreads();

            if (j < qt) {
                const int kv0 = (j + 1) * 64;
                #pragma unroll
                for (int i = 0; i < 4; ++i) {
                    kreg[i] = *(const f32x4*)(Kbh + (size_t)(kv0 + r0 + 16 * i) * DH_ + c0);
                    vreg[i] = *(const f32x4*)(Vbh + (size_t)(kv0 + r0 + 16 * i) * DH_ + c0);
                }
            }

            f32x4 sacc[4];
            #pragma unroll
            for (int ct = 0; ct < 4; ++ct) {
                f32x4 acc = (f32x4)0.0f;
                #pragma unroll
                for (int s = 0; s < 2; ++s) {
                    bf16x8 bk = *(const bf16x8*)&Kl[(16 * ct + l15) * LDK + 32 * s + quad * 8];
                    acc = __builtin_amdgcn_mfma_f32_16x16x32_bf16(qf[s], bk, acc, 0, 0, 0);
                }
                sacc[ct] = acc;
            }

            if (j == qt) {
                #pragma unroll
                for (int ct = 0; ct < 4; ++ct) {
                    const int keyl = 16 * ct + l15;
                    #pragma unroll
                    for (int r = 0; r < 4; ++r)
                        if (keyl > wave * 16 + quad * 4 + r) sacc[ct][r] = -1e30f;
                }
            }

            #pragma unroll
            for (int r = 0; r < 4; ++r) {
                float mx = fmaxf(fmaxf(sacc[0][r], sacc[1][r]), fmaxf(sacc[2][r], sacc[3][r]));
                mx = fmaxf(mx, __shfl_xor(mx, 1));
                mx = fmaxf(mx, __shfl_xor(mx, 2));
                mx = fmaxf(mx, __shfl_xor(mx, 4));
                mx = fmaxf(mx, __shfl_xor(mx, 8));
                const float mnew  = fmaxf(m_run[r], mx);
                const float alpha = exp2f(m_run[r] - mnew);
                float sum = 0.0f;
                #pragma unroll
                for (int ct = 0; ct < 4; ++ct) {
                    const float pv = exp2f(sacc[ct][r] - mnew);
                    sacc[ct][r] = pv;
                    sum += pv;
                }
                sum += __shfl_xor(sum, 1);
                sum += __shfl_xor(sum, 2);
                sum += __shfl_xor(sum, 4);
                sum += __shfl_xor(sum, 8);
                l_run[r] = l_run[r] * alpha + sum;
                m_run[r] = mnew;
                #pragma unroll
                for (int ct = 0; ct < 4; ++ct) o_acc[ct][r] *= alpha;
            }

            #pragma unroll
            for (int ct = 0; ct < 4; ++ct)
                #pragma unroll
                for (int r = 0; r < 4; ++r)
                    Pl[wave][(quad * 4 + r) * LDK + 16 * ct + l15] = (bf16)sacc[ct][r];

            bf16x8 pa[2];
            #pragma unroll
            for (int s = 0; s < 2; ++s)
                pa[s] = *(const bf16x8*)&Pl[wave][l15 * LDK + 32 * s + quad * 8];

            #pragma unroll
            for (int ct = 0; ct < 4; ++ct)
                #pragma unroll
                for (int s = 0; s < 2; ++s) {
                    bf16x8 bv = *(const bf16x8*)&Vt[(16 * ct + l15) * LDK + 32 * s + quad * 8];
                    o_acc[ct] = __builtin_amdgcn_mfma_f32_16x16x32_bf16(pa[s], bv, o_acc[ct], 0, 0, 0);
                }
        }

        #pragma unroll
        for (int ct = 0; ct < 4; ++ct)
            #pragma unroll
            for (int r = 0; r < 4; ++r) {
                const int qrow = q0 + wave * 16 + quad * 4 + r;
                O[((size_t)b * L_ + qrow) * (H_ * DH_) + h * DH_ + (16 * ct + l15)] =
                    o_acc[ct][r] / l_run[r];
            }
    }
}

extern "C" void kernel_launch(void* const* d_in, const int* in_sizes, int n_in,
                              void* d_out, int out_size, void* d_ws, size_t ws_size,
                              hipStream_t stream) {
    const float* q = (const float*)d_in[0];
    const float* k = (const float*)d_in[1];
    const float* v = (const float*)d_in[2];
    float* out = (float*)d_out;
    const size_t need = 2ull * (size_t)(B_ * H_) * L_ * DH_ * sizeof(bf16);  // 33.5 MB
    if (ws_size >= need) {
        bf16* Kb  = (bf16*)d_ws;
        bf16* Vtg = Kb + (size_t)(B_ * H_) * L_ * DH_;
        prep<<<dim3(B_ * H_ * (L_ / 64)), dim3(256), 0, stream>>>(k, v, Kb, Vtg);
        fa_fwd3<<<dim3(512), dim3(256), 0, stream>>>(q, Kb, Vtg, out);
    } else {
        fa_fwd<<<dim3(B_ * H_ * 16), dim3(256), 0, stream>>>(q, k, v, out);
    }
}

// Round 10
// 180.384 us; speedup vs baseline: 1.0843x; 1.0843x over previous
//
#include <hip/hip_runtime.h>
#include <hip/hip_bf16.h>

#define B_   4
#define H_   16
#define L_   2048
#define DH_  64
#define QSCALE 0.1803368801111204f  // (1/sqrt(64)) * log2(e): scores in log2 domain
#define LDK  72                     // fallback-kernel padded stride

typedef __bf16 bf16;
typedef __bf16 bf16x4 __attribute__((ext_vector_type(4)));
typedef __bf16 bf16x8 __attribute__((ext_vector_type(8)));
typedef float  f32x4  __attribute__((ext_vector_type(4)));

typedef const __attribute__((address_space(1))) unsigned int* gptr_t;
typedef __attribute__((address_space(3))) unsigned int* lptr_t;

__device__ __forceinline__ void load_lds16(const bf16* g, bf16* l) {
    // 16B per lane, LDS dest = wave-uniform base + lane*16
    __builtin_amdgcn_global_load_lds((gptr_t)(const void*)g, (lptr_t)(void*)l, 16, 0, 0);
}

__device__ __forceinline__ float exp2_fast(float x) {
#if __has_builtin(__builtin_amdgcn_exp2f)
    // single v_exp_f32 (2^x); compiler-visible intrinsic, fully scheduled.
    // -1e30 underflows to +0 (masked lanes), exactly what we need.
    return __builtin_amdgcn_exp2f(x);
#else
    return exp2f(x);
#endif
}

// ---------------- prep: K -> bf16 swizzled [bh][key][64], V -> bf16 transposed
// swizzled [bh][dh][2048].  Swizzle: within each 128B row/segment, 16B block c
// stored at slot c ^ (row & 7)  -> conflict-free ds_read_b128 later.
__global__ __launch_bounds__(256, 4)
void prep(const float* __restrict__ K, const float* __restrict__ V,
          bf16* __restrict__ Kb, bf16* __restrict__ Vtg)
{
    __shared__ bf16 tl[64 * 72];   // transposed V tile [dh][key], padded
    const int t   = threadIdx.x;
    const int r   = t >> 2;        // row 0..63
    const int c4  = t & 3;         // 16-col group
    const int bid = blockIdx.x;
    const int kt  = bid & 31;
    const int bh  = bid >> 5;

    const float* Kp = K + ((size_t)bh * L_ + kt * 64) * DH_;
    const float* Vp = V + ((size_t)bh * L_ + kt * 64) * DH_;
    bf16* Kbp = Kb  + (size_t)bh * (L_ * DH_) + (size_t)(kt * 64) * DH_;
    bf16* Vtp = Vtg + (size_t)bh * (DH_ * L_) + kt * 64;

    { // K: cvt + swizzle (row-major [key][dh])
        const float* src = Kp + r * DH_ + c4 * 16;
        f32x4 a = *(const f32x4*)(src);
        f32x4 b = *(const f32x4*)(src + 4);
        f32x4 c = *(const f32x4*)(src + 8);
        f32x4 d = *(const f32x4*)(src + 12);
        bf16x8 lo, hi;
        #pragma unroll
        for (int j = 0; j < 4; ++j) {
            lo[j] = (bf16)a[j]; lo[j + 4] = (bf16)b[j];
            hi[j] = (bf16)c[j]; hi[j + 4] = (bf16)d[j];
        }
        const int b0 = 2 * c4, b1 = 2 * c4 + 1;
        *(bf16x8*)(Kbp + r * 64 + (b0 ^ (r & 7)) * 8) = lo;
        *(bf16x8*)(Kbp + r * 64 + (b1 ^ (r & 7)) * 8) = hi;
    }
    { // V: cvt + transpose via LDS
        const float* src = Vp + r * DH_ + c4 * 16;
        f32x4 a = *(const f32x4*)(src);
        f32x4 b = *(const f32x4*)(src + 4);
        f32x4 c = *(const f32x4*)(src + 8);
        f32x4 d = *(const f32x4*)(src + 12);
        #pragma unroll
        for (int j = 0; j < 4; ++j) {
            tl[(c4 * 16 + j)      * 72 + r] = (bf16)a[j];
            tl[(c4 * 16 + 4 + j)  * 72 + r] = (bf16)b[j];
            tl[(c4 * 16 + 8 + j)  * 72 + r] = (bf16)c[j];
            tl[(c4 * 16 + 12 + j) * 72 + r] = (bf16)d[j];
        }
    }
    __syncthreads();
    { // write Vtg rows (dh-major), swizzled within the 64-key tile segment
        const int d = r;
        #pragma unroll
        for (int bi = 0; bi < 2; ++bi) {
            const int blk = 2 * c4 + bi;
            bf16x8 v;
            #pragma unroll
            for (int j = 0; j < 8; ++j) v[j] = tl[d * 72 + blk * 8 + j];
            *(bf16x8*)(Vtp + (size_t)d * L_ + (blk ^ (d & 7)) * 8) = v;
        }
    }
}

// ---------------- main: R13 — R3 structure (fastest proven: 80.2 µs) + VALU diet.
// Br=64 (wave = 16 query rows), pass pair (s, 31-s) -> 33 iters for EVERY
// block; grid 1024 = 4 blocks/CU; staged LDS double-buffer, 1 barrier/iter.
// New vs R3: (a) exp2 via __builtin_amdgcn_exp2f (single v_exp_f32; no OCML
// wrapper), __has_builtin-guarded; (b) bv LDS reads hoisted into registers
// BEFORE the exp/mask VALU stretch (ds latency hides under VALU; PV runs from
// regs). No sync-structure change of any kind.
__global__ __launch_bounds__(256, 4)
void fa_fwd3(const float* __restrict__ Q, const bf16* __restrict__ Kb,
             const bf16* __restrict__ Vtg, float* __restrict__ O)
{
    __shared__ __align__(16) bf16 smem[2][2][64 * 64];  // [buf][K=0,V=1] 32 KB
    __shared__ __align__(16) bf16 Pl[4][16 * 64];       // per-wave P, swizzled, 8 KB

    const int tid  = threadIdx.x;
    const int wave = tid >> 6;
    const int lane = tid & 63;
    const int quad = lane >> 4;
    const int l15  = lane & 15;

    const int u    = blockIdx.x;      // 1024 blocks
    const int bh   = u & 63;          // bh%8 == u%8 -> per-XCD K/V L2 reuse
    const int s    = u >> 6;          // 0..15 -> pair (s, 31-s)

    const int h    = bh & 15;
    const int b    = bh >> 4;

    const float* Qbh = Q + (size_t)bh * L_ * DH_;
    const bf16* Kbh  = Kb  + (size_t)bh * (L_ * DH_);
    const bf16* Vbh  = Vtg + (size_t)bh * (DH_ * L_);

    const int Rw = 16 * wave;       // staging slice (K rows / V dh rows)
    const int lr = lane >> 3;       // sub-row 0..7
    const int lb = lane & 7;        // 16B block slot

    bf16x8 vone;
    #pragma unroll
    for (int jj = 0; jj < 8; ++jj) vone[jj] = (bf16)1.0f;

    int swb[2];
    #pragma unroll
    for (int ss = 0; ss < 2; ++ss) swb[ss] = ((4 * ss + quad) ^ (l15 & 7)) * 8;

    for (int pass = 0; pass < 2; ++pass) {
        const int qt   = pass ? (31 - s) : s;   // 64-row Q tile index 0..31
        const int q0   = qt * 64;
        const int jmax = qt;                    // k-tiles 0..qt (33 iters total/block)

        // Q frag as B-operand (B[k=dh][n=qrow]: n=l15, k=quad*8+j), scale folded
        bf16x8 qf[2];
        {
            const int row = q0 + 16 * wave + l15;
            const float* qp = Qbh + (size_t)row * DH_ + quad * 8;
            #pragma unroll
            for (int ss = 0; ss < 2; ++ss) {
                f32x4 a = *(const f32x4*)(qp + ss * 32);
                f32x4 c = *(const f32x4*)(qp + ss * 32 + 4);
                #pragma unroll
                for (int jj = 0; jj < 4; ++jj) {
                    qf[ss][jj]     = (bf16)(a[jj] * QSCALE);
                    qf[ss][jj + 4] = (bf16)(c[jj] * QSCALE);
                }
            }
        }

        f32x4 o_acc[4];
        f32x4 l_acc = (f32x4)0.0f;
        #pragma unroll
        for (int ct = 0; ct < 4; ++ct) o_acc[ct] = (f32x4)0.0f;

        // prologue: tile 0 -> buf 0
        {
            const bf16* kg = Kbh + (size_t)(Rw + lr) * 64 + lb * 8;
            const bf16* vg = Vbh + (size_t)(Rw + lr) * L_ + lb * 8;
            bf16* kl = &smem[0][0][Rw * 64];
            bf16* vl = &smem[0][1][Rw * 64];
            load_lds16(kg, kl);              load_lds16(kg + 8 * 64, kl + 8 * 64);
            load_lds16(vg, vl);              load_lds16(vg + (size_t)8 * L_, vl + 8 * 64);
        }

        for (int j = 0; j <= jmax; ++j) {
            __syncthreads();   // drains async loads (tile j) + buffer-reuse fence
            const int cur = j & 1;

            if (j < jmax) {    // issue tile j+1
                const int nb  = cur ^ 1;
                const int kv0 = (j + 1) * 64;
                const bf16* kg = Kbh + (size_t)(kv0 + Rw + lr) * 64 + lb * 8;
                const bf16* vg = Vbh + (size_t)(Rw + lr) * L_ + kv0 + lb * 8;
                bf16* kl = &smem[nb][0][Rw * 64];
                bf16* vl = &smem[nb][1][Rw * 64];
                load_lds16(kg, kl);          load_lds16(kg + 8 * 64, kl + 8 * 64);
                load_lds16(vg, vl);          load_lds16(vg + (size_t)8 * L_, vl + 8 * 64);
            }

            const bf16* Kl = smem[cur][0];
            const bf16* Vt = smem[cur][1];

            // K frags (A[m=key]: m=l15, k=quad*8+j)
            bf16x8 bk[4][2];
            #pragma unroll
            for (int ct = 0; ct < 4; ++ct)
                #pragma unroll
                for (int ss = 0; ss < 2; ++ss)
                    bk[ct][ss] = *(const bf16x8*)&Kl[(16 * ct + l15) * 64 + swb[ss]];

            // V frags -> regs NOW: ds latency hides under S-MFMA + exp VALU below
            bf16x8 bv[4][2];
            #pragma unroll
            for (int ct = 0; ct < 4; ++ct)
                #pragma unroll
                for (int ss = 0; ss < 2; ++ss)
                    bv[ct][ss] = *(const bf16x8*)&Vt[(16 * ct + l15) * 64 + swb[ss]];

            // S^T = K (Q*scale)^T : C-layout lane holds key=16ct+quad*4+r, qrow=l15
            f32x4 sacc[4];
            #pragma unroll
            for (int ct = 0; ct < 4; ++ct) {
                f32x4 acc = (f32x4)0.0f;
                #pragma unroll
                for (int ss = 0; ss < 2; ++ss)
                    acc = __builtin_amdgcn_mfma_f32_16x16x32_bf16(bk[ct][ss], qf[ss], acc, 0, 0, 0);
                sacc[ct] = acc;
            }

            if (j == jmax) {   // diagonal tile: mask key > row (within-tile coords)
                const int rlim = 16 * wave + l15;
                #pragma unroll
                for (int ct = 0; ct < 4; ++ct) {
                    #pragma unroll
                    for (int r = 0; r < 4; ++r)
                        if (16 * ct + quad * 4 + r > rlim) sacc[ct][r] = -1e30f;
                }
            }

            // P = exp2(S), pack 4 consecutive keys (r=0..3) -> one b64 write
            #pragma unroll
            for (int ct = 0; ct < 4; ++ct) {
                bf16x4 pk;
                #pragma unroll
                for (int r = 0; r < 4; ++r) pk[r] = (bf16)exp2_fast(sacc[ct][r]);
                const int blk = 2 * ct + (quad >> 1);
                *(bf16x4*)&Pl[wave][l15 * 64 + ((blk ^ (l15 & 7)) * 8) + (quad & 1) * 4] = pk;
            }
            // A-frag read (A[m=qrow]: m=l15, k=quad*8+j), same swizzle
            bf16x8 pa[2];
            #pragma unroll
            for (int ss = 0; ss < 2; ++ss)
                pa[ss] = *(const bf16x8*)&Pl[wave][l15 * 64 + swb[ss]];

            // O += P V (bv in regs) ;  l += P * ones
            __builtin_amdgcn_s_setprio(1);
            #pragma unroll
            for (int ct = 0; ct < 4; ++ct)
                #pragma unroll
                for (int ss = 0; ss < 2; ++ss)
                    o_acc[ct] = __builtin_amdgcn_mfma_f32_16x16x32_bf16(pa[ss], bv[ct][ss], o_acc[ct], 0, 0, 0);
            #pragma unroll
            for (int ss = 0; ss < 2; ++ss)
                l_acc = __builtin_amdgcn_mfma_f32_16x16x32_bf16(pa[ss], vone, l_acc, 0, 0, 0);
            __builtin_amdgcn_s_setprio(0);
        }
        __syncthreads();   // buffers free before next pass's prologue

        // epilogue: O / l (l replicated across lanes; C-layout row=quad*4+r)
        #pragma unroll
        for (int r = 0; r < 4; ++r) {
            const float inv = 1.0f / l_acc[r];
            const int qrow = q0 + 16 * wave + quad * 4 + r;
            float* op = &O[((size_t)b * L_ + qrow) * (H_ * DH_) + h * DH_];
            #pragma unroll
            for (int ct = 0; ct < 4; ++ct)
                op[16 * ct + l15] = o_acc[ct][r] * inv;
        }
    }
}

// ---------------- fallback (R3 kernel) if ws too small ----------------
__global__ __launch_bounds__(256, 4)
void fa_fwd(const float* __restrict__ Q, const float* __restrict__ K,
            const float* __restrict__ V, float* __restrict__ O)
{
    __shared__ __align__(16) bf16 Kl[64 * LDK];
    __shared__ __align__(16) bf16 Vt[64 * LDK];
    __shared__ __align__(16) bf16 Pl[4][16 * LDK];

    const int tid  = threadIdx.x;
    const int wave = tid >> 6;
    const int lane = tid & 63;
    const int quad = lane >> 4;
    const int l15  = lane & 15;

    const int u    = blockIdx.x;
    const int xcd  = u & 7;
    const int p    = u >> 3;
    const int bh   = xcd * 8 + (p & 7);
    const int pidx = p >> 3;
    const int h    = bh & 15;
    const int b    = bh >> 4;

    const float* Qbh = Q + (size_t)bh * L_ * DH_;
    const float* Kbh = K + (size_t)bh * L_ * DH_;
    const float* Vbh = V + (size_t)bh * L_ * DH_;

    const int r0 = tid >> 4;
    const int c0 = (tid & 15) * 4;

    for (int pass = 0; pass < 2; ++pass) {
        const int qt = pass ? (31 - pidx) : pidx;
        const int q0 = qt * 64;

        bf16x8 qf[2];
        {
            const int row = q0 + wave * 16 + l15;
            const float* qp = Qbh + (size_t)row * DH_ + quad * 8;
            #pragma unroll
            for (int s = 0; s < 2; ++s) {
                f32x4 a = *(const f32x4*)(qp + s * 32);
                f32x4 c = *(const f32x4*)(qp + s * 32 + 4);
                #pragma unroll
                for (int jj = 0; jj < 4; ++jj) {
                    qf[s][jj]     = (bf16)(a[jj] * QSCALE);
                    qf[s][jj + 4] = (bf16)(c[jj] * QSCALE);
                }
            }
        }

        float m_run[4], l_run[4];
        f32x4 o_acc[4];
        #pragma unroll
        for (int r = 0; r < 4; ++r) { m_run[r] = -1e30f; l_run[r] = 0.0f; }
        #pragma unroll
        for (int ct = 0; ct < 4; ++ct) o_acc[ct] = (f32x4)0.0f;

        f32x4 kreg[4], vreg[4];
        #pragma unroll
        for (int i = 0; i < 4; ++i) {
            kreg[i] = *(const f32x4*)(Kbh + (size_t)(r0 + 16 * i) * DH_ + c0);
            vreg[i] = *(const f32x4*)(Vbh + (size_t)(r0 + 16 * i) * DH_ + c0);
        }

        for (int j = 0; j <= qt; ++j) {
            __syncthreads();
            #pragma unroll
            for (int i = 0; i < 4; ++i) {
                const int row = r0 + 16 * i;
                bf16x4 kb;
                #pragma unroll
                for (int c = 0; c < 4; ++c) kb[c] = (bf16)kreg[i][c];
                *(bf16x4*)&Kl[row * LDK + c0] = kb;
                Vt[(c0 + 0) * LDK + row] = (bf16)vreg[i][0];
                Vt[(c0 + 1) * LDK + row] = (bf16)vreg[i][1];
                Vt[(c0 + 2) * LDK + row] = (bf16)vreg[i][2];
                Vt[(c0 + 3) * LDK + row] = (bf16)vreg[i][3];
            }
            __syncthreads();

            if (j < qt) {
                const int kv0 = (j + 1) * 64;
                #pragma unroll
                for (int i = 0; i < 4; ++i) {
                    kreg[i] = *(const f32x4*)(Kbh + (size_t)(kv0 + r0 + 16 * i) * DH_ + c0);
                    vreg[i] = *(const f32x4*)(Vbh + (size_t)(kv0 + r0 + 16 * i) * DH_ + c0);
                }
            }

            f32x4 sacc[4];
            #pragma unroll
            for (int ct = 0; ct < 4; ++ct) {
                f32x4 acc = (f32x4)0.0f;
                #pragma unroll
                for (int s = 0; s < 2; ++s) {
                    bf16x8 bk = *(const bf16x8*)&Kl[(16 * ct + l15) * LDK + 32 * s + quad * 8];
                    acc = __builtin_amdgcn_mfma_f32_16x16x32_bf16(qf[s], bk, acc, 0, 0, 0);
                }
                sacc[ct] = acc;
            }

            if (j == qt) {
                #pragma unroll
                for (int ct = 0; ct < 4; ++ct) {
                    const int keyl = 16 * ct + l15;
                    #pragma unroll
                    for (int r = 0; r < 4; ++r)
                        if (keyl > wave * 16 + quad * 4 + r) sacc[ct][r] = -1e30f;
                }
            }

            #pragma unroll
            for (int r = 0; r < 4; ++r) {
                float mx = fmaxf(fmaxf(sacc[0][r], sacc[1][r]), fmaxf(sacc[2][r], sacc[3][r]));
                mx = fmaxf(mx, __shfl_xor(mx, 1));
                mx = fmaxf(mx, __shfl_xor(mx, 2));
                mx = fmaxf(mx, __shfl_xor(mx, 4));
                mx = fmaxf(mx, __shfl_xor(mx, 8));
                const float mnew  = fmaxf(m_run[r], mx);
                const float alpha = exp2f(m_run[r] - mnew);
                float sum = 0.0f;
                #pragma unroll
                for (int ct = 0; ct < 4; ++ct) {
                    const float pv = exp2f(sacc[ct][r] - mnew);
                    sacc[ct][r] = pv;
                    sum += pv;
                }
                sum += __shfl_xor(sum, 1);
                sum += __shfl_xor(sum, 2);
                sum += __shfl_xor(sum, 4);
                sum += __shfl_xor(sum, 8);
                l_run[r] = l_run[r] * alpha + sum;
                m_run[r] = mnew;
                #pragma unroll
                for (int ct = 0; ct < 4; ++ct) o_acc[ct][r] *= alpha;
            }

            #pragma unroll
            for (int ct = 0; ct < 4; ++ct)
                #pragma unroll
                for (int r = 0; r < 4; ++r)
                    Pl[wave][(quad * 4 + r) * LDK + 16 * ct + l15] = (bf16)sacc[ct][r];

            bf16x8 pa[2];
            #pragma unroll
            for (int s = 0; s < 2; ++s)
                pa[s] = *(const bf16x8*)&Pl[wave][l15 * LDK + 32 * s + quad * 8];

            #pragma unroll
            for (int ct = 0; ct < 4; ++ct)
                #pragma unroll
                for (int s = 0; s < 2; ++s) {
                    bf16x8 bv = *(const bf16x8*)&Vt[(16 * ct + l15) * LDK + 32 * s + quad * 8];
                    o_acc[ct] = __builtin_amdgcn_mfma_f32_16x16x32_bf16(pa[s], bv, o_acc[ct], 0, 0, 0);
                }
        }

        #pragma unroll
        for (int ct = 0; ct < 4; ++ct)
            #pragma unroll
            for (int r = 0; r < 4; ++r) {
                const int qrow = q0 + wave * 16 + quad * 4 + r;
                O[((size_t)b * L_ + qrow) * (H_ * DH_) + h * DH_ + (16 * ct + l15)] =
                    o_acc[ct][r] / l_run[r];
            }
    }
}

extern "C" void kernel_launch(void* const* d_in, const int* in_sizes, int n_in,
                              void* d_out, int out_size, void* d_ws, size_t ws_size,
                              hipStream_t stream) {
    const float* q = (const float*)d_in[0];
    const float* k = (const float*)d_in[1];
    const float* v = (const float*)d_in[2];
    float* out = (float*)d_out;
    const size_t need = 2ull * (size_t)(B_ * H_) * L_ * DH_ * sizeof(bf16);  // 33.5 MB
    if (ws_size >= need) {
        bf16* Kb  = (bf16*)d_ws;
        bf16* Vtg = Kb + (size_t)(B_ * H_) * L_ * DH_;
        prep<<<dim3(B_ * H_ * (L_ / 64)), dim3(256), 0, stream>>>(k, v, Kb, Vtg);
        fa_fwd3<<<dim3(1024), dim3(256), 0, stream>>>(q, Kb, Vtg, out);
    } else {
        fa_fwd<<<dim3(B_ * H_ * 16), dim3(256), 0, stream>>>(q, k, v, out);
    }
}